// Round 2
// baseline (1844.533 us; speedup 1.0000x reference)
//
#include <hip/hip_runtime.h>

typedef float f32x4 __attribute__((ext_vector_type(4)));
typedef short bf16x8 __attribute__((ext_vector_type(8)));

#define DEVI __device__ __forceinline__

// ---------- constants (problem shape is fixed) ----------
constexpr int Bn = 2;          // batch
constexpr int Sn = 4096;       // seq
constexpr int Hn = 16;         // heads
constexpr int Dn = 128;        // head dim
constexpr int En = 2048;       // d_model = Hn*Dn
constexpr int Mtot = Bn * Sn;  // 8192 token rows

DEVI unsigned short f2bf(float f) {
  unsigned u = __float_as_uint(f);
  u += 0x7fffu + ((u >> 16) & 1u);
  return (unsigned short)(u >> 16);
}
DEVI float bf2f(unsigned short h) {
  return __uint_as_float(((unsigned)h) << 16);
}

DEVI void async16(const void* g, void* l) {
  __builtin_amdgcn_global_load_lds(
      (const __attribute__((address_space(1))) void*)g,
      (__attribute__((address_space(3))) void*)l, 16, 0, 0);
}

// ---------- fp32 -> bf16 convert ----------
__global__ void cvt_kernel(const float* __restrict__ in, ushort* __restrict__ out) {
  size_t i = ((size_t)blockIdx.x * 256 + threadIdx.x) * 4;
  float4 v = *(const float4*)&in[i];
  ushort4 o;
  o.x = f2bf(v.x); o.y = f2bf(v.y); o.z = f2bf(v.z); o.w = f2bf(v.w);
  *(ushort4*)&out[i] = o;
}

// ---------- RoPE in place on [Mtot, En] bf16, interleaved pairs ----------
// scale: extra multiplier folded into the output (softmax scale for Q).
__global__ void rope_kernel(ushort* __restrict__ Q, float scale) {
  int row = blockIdx.x;           // 0..Mtot-1
  int s = row & (Sn - 1);
  int t = threadIdx.x;
  size_t base = (size_t)row * En;
#pragma unroll
  for (int rep = 0; rep < 4; ++rep) {
    int p = rep * 256 + t;        // pair index 0..1023
    int e = p * 2;
    int pp = (e & (Dn - 1)) >> 1; // pair index within head, 0..63
    float inv = exp2f(-(float)pp * (13.287712379549449f / 64.0f));
    float ang = (float)s * inv;
    float c = cosf(ang), sn = sinf(ang);
    unsigned v = *(unsigned*)&Q[base + e];
    float q0 = bf2f((unsigned short)(v & 0xffffu));
    float q1 = bf2f((unsigned short)(v >> 16));
    float n0 = (q0 * c - q1 * sn) * scale;
    float n1 = (q1 * c + q0 * sn) * scale;
    unsigned outv = (unsigned)f2bf(n0) | ((unsigned)f2bf(n1) << 16);
    *(unsigned*)&Q[base + e] = outv;
  }
}

// ---------- GEMM: C[M,N] = A[M,K] * B[N,K]^T, bf16 in, fp32 acc ----------
template <int EPI>
__global__ __launch_bounds__(256) void gemm_bt(const ushort* __restrict__ A,
                                               const ushort* __restrict__ Bm,
                                               void* __restrict__ Cv) {
  __shared__ ushort As[128 * 64];
  __shared__ ushort Bs[128 * 64];
  const int t = threadIdx.x;
  const int lane = t & 63, w = t >> 6;
  const int ln = lane & 15, gq = lane >> 4;
  const int m0 = blockIdx.y * 128, n0 = blockIdx.x * 128;
  const int rm = (w >> 1) * 64, rn = (w & 1) * 64;
  f32x4 acc[4][4] = {};

  for (int k0 = 0; k0 < En; k0 += 64) {
#pragma unroll
    for (int rep = 0; rep < 4; ++rep) {
      int c = rep * 256 + t;       // chunk 0..1023 (16B each)
      int row = c >> 3, c8 = c & 7;
      async16(&A[(size_t)(m0 + row) * En + k0 + c8 * 8],
              (char*)As + (rep * 256 + w * 64) * 16);
      async16(&Bm[(size_t)(n0 + row) * En + k0 + c8 * 8],
              (char*)Bs + (rep * 256 + w * 64) * 16);
    }
    __syncthreads();
#pragma unroll
    for (int kk = 0; kk < 64; kk += 32) {
      bf16x8 af[4], bf[4];
#pragma unroll
      for (int i = 0; i < 4; ++i)
        af[i] = *(const bf16x8*)&As[(rm + i * 16 + ln) * 64 + kk + gq * 8];
#pragma unroll
      for (int j = 0; j < 4; ++j)
        bf[j] = *(const bf16x8*)&Bs[(rn + j * 16 + ln) * 64 + kk + gq * 8];
#pragma unroll
      for (int i = 0; i < 4; ++i)
#pragma unroll
        for (int j = 0; j < 4; ++j)
          acc[i][j] = __builtin_amdgcn_mfma_f32_16x16x32_bf16(af[i], bf[j], acc[i][j], 0, 0, 0);
    }
    __syncthreads();
  }

  if constexpr (EPI == 0) {
    ushort* C = (ushort*)Cv;
#pragma unroll
    for (int i = 0; i < 4; ++i) {
      int row0 = m0 + rm + i * 16 + gq * 4;
#pragma unroll
      for (int j = 0; j < 4; ++j) {
        int col = n0 + rn + j * 16 + ln;
#pragma unroll
        for (int r = 0; r < 4; ++r)
          C[(size_t)(row0 + r) * En + col] = f2bf(acc[i][j][r]);
      }
    }
  } else if constexpr (EPI == 1) {
    ushort* Vt = (ushort*)Cv;
#pragma unroll
    for (int i = 0; i < 4; ++i) {
      int mrow = m0 + rm + i * 16 + gq * 4;   // token row (4 consecutive)
      int bb = mrow >> 12;                     // /Sn
      int ss = mrow & (Sn - 1);
#pragma unroll
      for (int j = 0; j < 4; ++j) {
        int col = n0 + rn + j * 16 + ln;       // e = h*128+d
        ushort4 pk;
        pk.x = f2bf(acc[i][j][0]); pk.y = f2bf(acc[i][j][1]);
        pk.z = f2bf(acc[i][j][2]); pk.w = f2bf(acc[i][j][3]);
        *(ushort4*)&Vt[((size_t)(bb * En + col)) * Sn + ss] = pk;
      }
    }
  } else {
    float* C = (float*)Cv;
#pragma unroll
    for (int i = 0; i < 4; ++i) {
      int row0 = m0 + rm + i * 16 + gq * 4;
#pragma unroll
      for (int j = 0; j < 4; ++j) {
        int col = n0 + rn + j * 16 + ln;
#pragma unroll
        for (int r = 0; r < 4; ++r)
          C[(size_t)(row0 + r) * En + col] = acc[i][j][r];
      }
    }
  }
}

// ---------- flash attention (causal), S^T formulation, R2 ----------
// Changes vs R1: padded LDS (conflict-free b128), reg-prefetch double buffer,
// pre-scaled Q (scale folded in RoPE), uniform-mask fast path, wave-level
// skip of fully-masked tiles, reversed q-tile order for load balance.
// Ks[64][136] row=kv j, col=d (pad 128->136; stride 272B == 16 mod 128 banks)
// Vs[128][72] row=d,    col=kv j (stride 144B)
// Ps[w][32][72] per-wave P: row=q i, col=kv j (stride 144B)
__global__ __launch_bounds__(256, 3) void flash_kernel(const ushort* __restrict__ Qb,
                                                       const ushort* __restrict__ Kb,
                                                       const ushort* __restrict__ Vt,
                                                       ushort* __restrict__ Ab) {
  __shared__ ushort Ks[64 * 136];
  __shared__ ushort Vs[128 * 72];
  __shared__ ushort Ps[4][32 * 72];
  const int t = threadIdx.x;
  const int lane = t & 63, w = t >> 6;
  const int ln = lane & 15, gq = lane >> 4;
  const int qt = gridDim.x - 1 - blockIdx.x;   // heavy tiles dispatch first
  const int q0 = qt * 128;
  const int bh = blockIdx.y;
  const int b = bh >> 4, h = bh & 15;

  // Q fragments (B-operand), already scaled by 1/sqrt(D)*log2(e) in RoPE.
  bf16x8 qf[2][4];
#pragma unroll
  for (int it = 0; it < 2; ++it) {
    int qrow = q0 + w * 32 + it * 16 + ln;
    size_t base = ((size_t)(b * Sn + qrow)) * En + h * Dn;
#pragma unroll
    for (int ks = 0; ks < 4; ++ks)
      qf[it][ks] = *(const bf16x8*)&Qb[base + ks * 32 + gq * 8];
  }

  f32x4 o[8][2] = {};                 // O^T acc: [dt][it]
  float m_prev[2] = {-1e30f, -1e30f};
  float l_prev[2] = {0.f, 0.f};
  const int jmax = q0 + 64;

  // register prefetch buffers (one 64-kv tile of K and V)
  uint4 kpre[4], vpre[4];
#pragma unroll
  for (int rep = 0; rep < 4; ++rep) {
    int c = rep * 256 + t;
    kpre[rep] = *(const uint4*)&Kb[((size_t)(b * Sn + 0 + (c >> 4))) * En + h * Dn + (c & 15) * 8];
    vpre[rep] = *(const uint4*)&Vt[((size_t)(b * En + h * Dn + (c >> 3))) * Sn + 0 + (c & 7) * 8];
  }

  for (int j0 = 0; j0 <= jmax; j0 += 64) {
    __syncthreads();   // (A) prev tile's LDS reads done; prefetch loads landed
#pragma unroll
    for (int rep = 0; rep < 4; ++rep) {
      int c = rep * 256 + t;
      *(uint4*)&Ks[(c >> 4) * 136 + (c & 15) * 8] = kpre[rep];
      *(uint4*)&Vs[(c >> 3) * 72 + (c & 7) * 8] = vpre[rep];
    }
    __syncthreads();   // (B) LDS writes visible (lgkm-only drain)

    const bool active = (j0 <= q0 + w * 32 + 31);   // wave-uniform

    f32x4 s[2][4] = {};
    if (active) {
#pragma unroll
      for (int jt = 0; jt < 4; ++jt) {
#pragma unroll
        for (int ks = 0; ks < 4; ++ks) {
          bf16x8 kf = *(const bf16x8*)&Ks[(jt * 16 + ln) * 136 + ks * 32 + gq * 8];
          s[0][jt] = __builtin_amdgcn_mfma_f32_16x16x32_bf16(kf, qf[0][ks], s[0][jt], 0, 0, 0);
          s[1][jt] = __builtin_amdgcn_mfma_f32_16x16x32_bf16(kf, qf[1][ks], s[1][jt], 0, 0, 0);
        }
      }
    }

    // prefetch next tile (register pressure is lowest here; consumed at next (A))
    if (j0 + 64 <= jmax) {
      int nj = j0 + 64;
#pragma unroll
      for (int rep = 0; rep < 4; ++rep) {
        int c = rep * 256 + t;
        kpre[rep] = *(const uint4*)&Kb[((size_t)(b * Sn + nj + (c >> 4))) * En + h * Dn + (c & 15) * 8];
        vpre[rep] = *(const uint4*)&Vt[((size_t)(b * En + h * Dn + (c >> 3))) * Sn + nj + (c & 7) * 8];
      }
    }

    if (active) {
      // online softmax per q column (lane owns column i = ln)
#pragma unroll
      for (int it = 0; it < 2; ++it) {
        int qrow = q0 + w * 32 + it * 16 + ln;
        bool needmask = (j0 + 63 > q0 + w * 32 + it * 16);  // wave-uniform
        float mx = -1e30f;
        if (needmask) {
#pragma unroll
          for (int jt = 0; jt < 4; ++jt)
#pragma unroll
            for (int r = 0; r < 4; ++r) {
              int j = j0 + jt * 16 + gq * 4 + r;
              float v = s[it][jt][r];
              v = (j > qrow) ? -1e30f : v;
              s[it][jt][r] = v;
              mx = fmaxf(mx, v);
            }
        } else {
#pragma unroll
          for (int jt = 0; jt < 4; ++jt)
#pragma unroll
            for (int r = 0; r < 4; ++r) mx = fmaxf(mx, s[it][jt][r]);
        }
        mx = fmaxf(mx, __shfl_xor(mx, 16));
        mx = fmaxf(mx, __shfl_xor(mx, 32));
        float mn = fmaxf(m_prev[it], mx);
        float alpha = __builtin_amdgcn_exp2f(m_prev[it] - mn);
        float sum = 0.f;
#pragma unroll
        for (int jt = 0; jt < 4; ++jt) {
#pragma unroll
          for (int r = 0; r < 4; ++r) {
            float p = __builtin_amdgcn_exp2f(s[it][jt][r] - mn);
            s[it][jt][r] = p;
            sum += p;
          }
        }
        sum += __shfl_xor(sum, 16);
        sum += __shfl_xor(sum, 32);
        l_prev[it] = l_prev[it] * alpha + sum;
        m_prev[it] = mn;
#pragma unroll
        for (int dt = 0; dt < 8; ++dt) o[dt][it] *= alpha;
#pragma unroll
        for (int jt = 0; jt < 4; ++jt) {
          ushort4 pk;
          pk.x = f2bf(s[it][jt][0]); pk.y = f2bf(s[it][jt][1]);
          pk.z = f2bf(s[it][jt][2]); pk.w = f2bf(s[it][jt][3]);
          *(ushort4*)&Ps[w][(it * 16 + ln) * 72 + jt * 16 + gq * 4] = pk;
        }
      }

      // PV: O^T[d][i] += sum_j Vs[d][j] * P[i][j]
#pragma unroll
      for (int ksj = 0; ksj < 2; ++ksj) {
        bf16x8 pf[2];
#pragma unroll
        for (int it = 0; it < 2; ++it)
          pf[it] = *(const bf16x8*)&Ps[w][(it * 16 + ln) * 72 + ksj * 32 + gq * 8];
#pragma unroll
        for (int dt = 0; dt < 8; ++dt) {
          bf16x8 vf = *(const bf16x8*)&Vs[(dt * 16 + ln) * 72 + ksj * 32 + gq * 8];
          o[dt][0] = __builtin_amdgcn_mfma_f32_16x16x32_bf16(vf, pf[0], o[dt][0], 0, 0, 0);
          o[dt][1] = __builtin_amdgcn_mfma_f32_16x16x32_bf16(vf, pf[1], o[dt][1], 0, 0, 0);
        }
      }
    }
  }

  // epilogue: normalize by 1/l, write Ab[b, qrow, h*128 + d]
#pragma unroll
  for (int it = 0; it < 2; ++it) {
    float inv = 1.f / l_prev[it];
    int qrow = q0 + w * 32 + it * 16 + ln;
    size_t base = ((size_t)(b * Sn + qrow)) * En + h * Dn;
#pragma unroll
    for (int dt = 0; dt < 8; ++dt) {
      ushort4 pk;
      pk.x = f2bf(o[dt][it][0] * inv);
      pk.y = f2bf(o[dt][it][1] * inv);
      pk.z = f2bf(o[dt][it][2] * inv);
      pk.w = f2bf(o[dt][it][3] * inv);
      *(ushort4*)&Ab[base + dt * 16 + gq * 4] = pk;
    }
  }
}

extern "C" void kernel_launch(void* const* d_in, const int* in_sizes, int n_in,
                              void* d_out, int out_size, void* d_ws, size_t ws_size,
                              hipStream_t stream) {
  const float* x  = (const float*)d_in[0];
  const float* Wq = (const float*)d_in[1];
  const float* Wk = (const float*)d_in[2];
  const float* Wv = (const float*)d_in[3];
  const float* Wo = (const float*)d_in[4];

  char* ws = (char*)d_ws;
  ushort* xb  = (ushort*)(ws + 0);           // 32 MiB  [Mtot, En]
  ushort* wqb = (ushort*)(ws + 33554432);    // 8 MiB
  ushort* wkb = (ushort*)(ws + 41943040);
  ushort* wvb = (ushort*)(ws + 50331648);
  ushort* wob = (ushort*)(ws + 58720256);
  ushort* Qb  = (ushort*)(ws + 67108864);    // 32 MiB
  ushort* Kb  = (ushort*)(ws + 100663296);   // 32 MiB
  ushort* Vt  = (ushort*)(ws + 134217728);   // 32 MiB  [B*En, Sn]
  ushort* Ab  = xb;                           // alias: xb dead after V GEMM

  cvt_kernel<<<dim3(Mtot * En / 1024), 256, 0, stream>>>(x, xb);
  cvt_kernel<<<dim3(En * En / 1024), 256, 0, stream>>>(Wq, wqb);
  cvt_kernel<<<dim3(En * En / 1024), 256, 0, stream>>>(Wk, wkb);
  cvt_kernel<<<dim3(En * En / 1024), 256, 0, stream>>>(Wv, wvb);
  cvt_kernel<<<dim3(En * En / 1024), 256, 0, stream>>>(Wo, wob);

  dim3 ggrid(En / 128, Mtot / 128);
  gemm_bt<0><<<ggrid, 256, 0, stream>>>(xb, wqb, (void*)Qb);
  gemm_bt<0><<<ggrid, 256, 0, stream>>>(xb, wkb, (void*)Kb);
  gemm_bt<1><<<ggrid, 256, 0, stream>>>(xb, wvb, (void*)Vt);

  // scale folded into Q: 1/sqrt(128) * log2(e)
  rope_kernel<<<dim3(Mtot), 256, 0, stream>>>(Qb, 0.08838834764831845f * 1.4426950408889634f);
  rope_kernel<<<dim3(Mtot), 256, 0, stream>>>(Kb, 1.0f);

  flash_kernel<<<dim3(Sn / 128, Bn * Hn), 256, 0, stream>>>(Qb, Kb, Vt, Ab);

  gemm_bt<2><<<ggrid, 256, 0, stream>>>(Ab, wob, d_out);
}

// Round 3
// 1197.620 us; speedup vs baseline: 1.5402x; 1.5402x over previous
//
#include <hip/hip_runtime.h>

typedef float f32x4 __attribute__((ext_vector_type(4)));
typedef short bf16x8 __attribute__((ext_vector_type(8)));

#define DEVI __device__ __forceinline__

// ---------- constants (problem shape is fixed) ----------
constexpr int Bn = 2;          // batch
constexpr int Sn = 4096;       // seq
constexpr int Hn = 16;         // heads
constexpr int Dn = 128;        // head dim
constexpr int En = 2048;       // d_model = Hn*Dn
constexpr int Mtot = Bn * Sn;  // 8192 token rows

DEVI unsigned short f2bf(float f) {
  unsigned u = __float_as_uint(f);
  u += 0x7fffu + ((u >> 16) & 1u);
  return (unsigned short)(u >> 16);
}
DEVI float bf2f(unsigned short h) {
  return __uint_as_float(((unsigned)h) << 16);
}

DEVI void async16(const void* g, void* l) {
  __builtin_amdgcn_global_load_lds(
      (const __attribute__((address_space(1))) void*)g,
      (__attribute__((address_space(3))) void*)l, 16, 0, 0);
}

// ---------- fp32 -> bf16 convert ----------
__global__ void cvt_kernel(const float* __restrict__ in, ushort* __restrict__ out) {
  size_t i = ((size_t)blockIdx.x * 256 + threadIdx.x) * 4;
  float4 v = *(const float4*)&in[i];
  ushort4 o;
  o.x = f2bf(v.x); o.y = f2bf(v.y); o.z = f2bf(v.z); o.w = f2bf(v.w);
  *(ushort4*)&out[i] = o;
}

// ---------- RoPE in place on [Mtot, En] bf16, interleaved pairs ----------
// scale: extra multiplier folded into the output (softmax scale for Q).
__global__ void rope_kernel(ushort* __restrict__ Q, float scale) {
  int row = blockIdx.x;           // 0..Mtot-1
  int s = row & (Sn - 1);
  int t = threadIdx.x;
  size_t base = (size_t)row * En;
#pragma unroll
  for (int rep = 0; rep < 4; ++rep) {
    int p = rep * 256 + t;        // pair index 0..1023
    int e = p * 2;
    int pp = (e & (Dn - 1)) >> 1; // pair index within head, 0..63
    float inv = exp2f(-(float)pp * (13.287712379549449f / 64.0f));
    float ang = (float)s * inv;
    float c = cosf(ang), sn = sinf(ang);
    unsigned v = *(unsigned*)&Q[base + e];
    float q0 = bf2f((unsigned short)(v & 0xffffu));
    float q1 = bf2f((unsigned short)(v >> 16));
    float n0 = (q0 * c - q1 * sn) * scale;
    float n1 = (q1 * c + q0 * sn) * scale;
    unsigned outv = (unsigned)f2bf(n0) | ((unsigned)f2bf(n1) << 16);
    *(unsigned*)&Q[base + e] = outv;
  }
}

// ---------- GEMM: C[M,N] = A[M,K] * B[N,K]^T, bf16 in, fp32 acc ----------
template <int EPI>
__global__ __launch_bounds__(256) void gemm_bt(const ushort* __restrict__ A,
                                               const ushort* __restrict__ Bm,
                                               void* __restrict__ Cv) {
  __shared__ ushort As[128 * 64];
  __shared__ ushort Bs[128 * 64];
  const int t = threadIdx.x;
  const int lane = t & 63, w = t >> 6;
  const int ln = lane & 15, gq = lane >> 4;
  const int m0 = blockIdx.y * 128, n0 = blockIdx.x * 128;
  const int rm = (w >> 1) * 64, rn = (w & 1) * 64;
  f32x4 acc[4][4] = {};

  for (int k0 = 0; k0 < En; k0 += 64) {
#pragma unroll
    for (int rep = 0; rep < 4; ++rep) {
      int c = rep * 256 + t;       // chunk 0..1023 (16B each)
      int row = c >> 3, c8 = c & 7;
      async16(&A[(size_t)(m0 + row) * En + k0 + c8 * 8],
              (char*)As + (rep * 256 + w * 64) * 16);
      async16(&Bm[(size_t)(n0 + row) * En + k0 + c8 * 8],
              (char*)Bs + (rep * 256 + w * 64) * 16);
    }
    __syncthreads();
#pragma unroll
    for (int kk = 0; kk < 64; kk += 32) {
      bf16x8 af[4], bf[4];
#pragma unroll
      for (int i = 0; i < 4; ++i)
        af[i] = *(const bf16x8*)&As[(rm + i * 16 + ln) * 64 + kk + gq * 8];
#pragma unroll
      for (int j = 0; j < 4; ++j)
        bf[j] = *(const bf16x8*)&Bs[(rn + j * 16 + ln) * 64 + kk + gq * 8];
#pragma unroll
      for (int i = 0; i < 4; ++i)
#pragma unroll
        for (int j = 0; j < 4; ++j)
          acc[i][j] = __builtin_amdgcn_mfma_f32_16x16x32_bf16(af[i], bf[j], acc[i][j], 0, 0, 0);
    }
    __syncthreads();
  }

  if constexpr (EPI == 0) {
    ushort* C = (ushort*)Cv;
#pragma unroll
    for (int i = 0; i < 4; ++i) {
      int row0 = m0 + rm + i * 16 + gq * 4;
#pragma unroll
      for (int j = 0; j < 4; ++j) {
        int col = n0 + rn + j * 16 + ln;
#pragma unroll
        for (int r = 0; r < 4; ++r)
          C[(size_t)(row0 + r) * En + col] = f2bf(acc[i][j][r]);
      }
    }
  } else if constexpr (EPI == 1) {
    ushort* Vt = (ushort*)Cv;
#pragma unroll
    for (int i = 0; i < 4; ++i) {
      int mrow = m0 + rm + i * 16 + gq * 4;   // token row (4 consecutive)
      int bb = mrow >> 12;                     // /Sn
      int ss = mrow & (Sn - 1);
#pragma unroll
      for (int j = 0; j < 4; ++j) {
        int col = n0 + rn + j * 16 + ln;       // e = h*128+d
        ushort4 pk;
        pk.x = f2bf(acc[i][j][0]); pk.y = f2bf(acc[i][j][1]);
        pk.z = f2bf(acc[i][j][2]); pk.w = f2bf(acc[i][j][3]);
        *(ushort4*)&Vt[((size_t)(bb * En + col)) * Sn + ss] = pk;
      }
    }
  } else {
    float* C = (float*)Cv;
#pragma unroll
    for (int i = 0; i < 4; ++i) {
      int row0 = m0 + rm + i * 16 + gq * 4;
#pragma unroll
      for (int j = 0; j < 4; ++j) {
        int col = n0 + rn + j * 16 + ln;
#pragma unroll
        for (int r = 0; r < 4; ++r)
          C[(size_t)(row0 + r) * En + col] = acc[i][j][r];
      }
    }
  }
}

// ---------- flash attention (causal), S^T formulation, R3 ----------
// R2 structure (padded LDS, reg-prefetch dbuf, folded scale, mask fast paths,
// reversed dispatch) with the spill fixed: __launch_bounds__(256,2) gives a
// 256-reg combined VGPR+AGPR budget, fitting the ~220-reg live set.
// Ks[64][136] row=kv j, col=d; Vs[128][72] row=d, col=kv j;
// Ps[w][32][72] per-wave P: row=q i, col=kv j.
__global__ __launch_bounds__(256, 2) void flash_kernel(const ushort* __restrict__ Qb,
                                                       const ushort* __restrict__ Kb,
                                                       const ushort* __restrict__ Vt,
                                                       ushort* __restrict__ Ab) {
  __shared__ ushort Ks[64 * 136];
  __shared__ ushort Vs[128 * 72];
  __shared__ ushort Ps[4][32 * 72];
  const int t = threadIdx.x;
  const int lane = t & 63, w = t >> 6;
  const int ln = lane & 15, gq = lane >> 4;
  const int qt = gridDim.x - 1 - blockIdx.x;   // heavy tiles dispatch first
  const int q0 = qt * 128;
  const int bh = blockIdx.y;
  const int b = bh >> 4, h = bh & 15;

  // Q fragments (B-operand), already scaled by 1/sqrt(D)*log2(e) in RoPE.
  bf16x8 qf[2][4];
#pragma unroll
  for (int it = 0; it < 2; ++it) {
    int qrow = q0 + w * 32 + it * 16 + ln;
    size_t base = ((size_t)(b * Sn + qrow)) * En + h * Dn;
#pragma unroll
    for (int ks = 0; ks < 4; ++ks)
      qf[it][ks] = *(const bf16x8*)&Qb[base + ks * 32 + gq * 8];
  }

  f32x4 o[8][2] = {};                 // O^T acc: [dt][it]
  float m_prev[2] = {-1e30f, -1e30f};
  float l_prev[2] = {0.f, 0.f};
  const int jmax = q0 + 64;

  // register prefetch buffers (one 64-kv tile of K and V)
  uint4 kpre[4], vpre[4];
#pragma unroll
  for (int rep = 0; rep < 4; ++rep) {
    int c = rep * 256 + t;
    kpre[rep] = *(const uint4*)&Kb[((size_t)(b * Sn + 0 + (c >> 4))) * En + h * Dn + (c & 15) * 8];
    vpre[rep] = *(const uint4*)&Vt[((size_t)(b * En + h * Dn + (c >> 3))) * Sn + 0 + (c & 7) * 8];
  }

  for (int j0 = 0; j0 <= jmax; j0 += 64) {
    __syncthreads();   // (A) prev tile's LDS reads done; prefetch loads landed
#pragma unroll
    for (int rep = 0; rep < 4; ++rep) {
      int c = rep * 256 + t;
      *(uint4*)&Ks[(c >> 4) * 136 + (c & 15) * 8] = kpre[rep];
      *(uint4*)&Vs[(c >> 3) * 72 + (c & 7) * 8] = vpre[rep];
    }
    __syncthreads();   // (B) LDS writes visible

    const bool active = (j0 <= q0 + w * 32 + 31);   // wave-uniform

    f32x4 s[2][4] = {};
    if (active) {
#pragma unroll
      for (int jt = 0; jt < 4; ++jt) {
#pragma unroll
        for (int ks = 0; ks < 4; ++ks) {
          bf16x8 kf = *(const bf16x8*)&Ks[(jt * 16 + ln) * 136 + ks * 32 + gq * 8];
          s[0][jt] = __builtin_amdgcn_mfma_f32_16x16x32_bf16(kf, qf[0][ks], s[0][jt], 0, 0, 0);
          s[1][jt] = __builtin_amdgcn_mfma_f32_16x16x32_bf16(kf, qf[1][ks], s[1][jt], 0, 0, 0);
        }
      }
    }

    // prefetch next tile (consumed at next barrier (A))
    if (j0 + 64 <= jmax) {
      int nj = j0 + 64;
#pragma unroll
      for (int rep = 0; rep < 4; ++rep) {
        int c = rep * 256 + t;
        kpre[rep] = *(const uint4*)&Kb[((size_t)(b * Sn + nj + (c >> 4))) * En + h * Dn + (c & 15) * 8];
        vpre[rep] = *(const uint4*)&Vt[((size_t)(b * En + h * Dn + (c >> 3))) * Sn + nj + (c & 7) * 8];
      }
    }

    if (active) {
      // online softmax per q column (lane owns column i = ln)
#pragma unroll
      for (int it = 0; it < 2; ++it) {
        int qrow = q0 + w * 32 + it * 16 + ln;
        bool needmask = (j0 + 63 > q0 + w * 32 + it * 16);  // wave-uniform
        float mx = -1e30f;
        if (needmask) {
#pragma unroll
          for (int jt = 0; jt < 4; ++jt)
#pragma unroll
            for (int r = 0; r < 4; ++r) {
              int j = j0 + jt * 16 + gq * 4 + r;
              float v = s[it][jt][r];
              v = (j > qrow) ? -1e30f : v;
              s[it][jt][r] = v;
              mx = fmaxf(mx, v);
            }
        } else {
#pragma unroll
          for (int jt = 0; jt < 4; ++jt)
#pragma unroll
            for (int r = 0; r < 4; ++r) mx = fmaxf(mx, s[it][jt][r]);
        }
        mx = fmaxf(mx, __shfl_xor(mx, 16));
        mx = fmaxf(mx, __shfl_xor(mx, 32));
        float mn = fmaxf(m_prev[it], mx);
        float alpha = __builtin_amdgcn_exp2f(m_prev[it] - mn);
        float sum = 0.f;
#pragma unroll
        for (int jt = 0; jt < 4; ++jt) {
#pragma unroll
          for (int r = 0; r < 4; ++r) {
            float p = __builtin_amdgcn_exp2f(s[it][jt][r] - mn);
            s[it][jt][r] = p;
            sum += p;
          }
        }
        sum += __shfl_xor(sum, 16);
        sum += __shfl_xor(sum, 32);
        l_prev[it] = l_prev[it] * alpha + sum;
        m_prev[it] = mn;
#pragma unroll
        for (int dt = 0; dt < 8; ++dt) o[dt][it] *= alpha;
#pragma unroll
        for (int jt = 0; jt < 4; ++jt) {
          ushort4 pk;
          pk.x = f2bf(s[it][jt][0]); pk.y = f2bf(s[it][jt][1]);
          pk.z = f2bf(s[it][jt][2]); pk.w = f2bf(s[it][jt][3]);
          *(ushort4*)&Ps[w][(it * 16 + ln) * 72 + jt * 16 + gq * 4] = pk;
        }
      }

      // PV: O^T[d][i] += sum_j Vs[d][j] * P[i][j]
#pragma unroll
      for (int ksj = 0; ksj < 2; ++ksj) {
        bf16x8 pf[2];
#pragma unroll
        for (int it = 0; it < 2; ++it)
          pf[it] = *(const bf16x8*)&Ps[w][(it * 16 + ln) * 72 + ksj * 32 + gq * 8];
#pragma unroll
        for (int dt = 0; dt < 8; ++dt) {
          bf16x8 vf = *(const bf16x8*)&Vs[(dt * 16 + ln) * 72 + ksj * 32 + gq * 8];
          o[dt][0] = __builtin_amdgcn_mfma_f32_16x16x32_bf16(vf, pf[0], o[dt][0], 0, 0, 0);
          o[dt][1] = __builtin_amdgcn_mfma_f32_16x16x32_bf16(vf, pf[1], o[dt][1], 0, 0, 0);
        }
      }
    }
  }

  // epilogue: normalize by 1/l, write Ab[b, qrow, h*128 + d]
#pragma unroll
  for (int it = 0; it < 2; ++it) {
    float inv = 1.f / l_prev[it];
    int qrow = q0 + w * 32 + it * 16 + ln;
    size_t base = ((size_t)(b * Sn + qrow)) * En + h * Dn;
#pragma unroll
    for (int dt = 0; dt < 8; ++dt) {
      ushort4 pk;
      pk.x = f2bf(o[dt][it][0] * inv);
      pk.y = f2bf(o[dt][it][1] * inv);
      pk.z = f2bf(o[dt][it][2] * inv);
      pk.w = f2bf(o[dt][it][3] * inv);
      *(ushort4*)&Ab[base + dt * 16 + gq * 4] = pk;
    }
  }
}

extern "C" void kernel_launch(void* const* d_in, const int* in_sizes, int n_in,
                              void* d_out, int out_size, void* d_ws, size_t ws_size,
                              hipStream_t stream) {
  const float* x  = (const float*)d_in[0];
  const float* Wq = (const float*)d_in[1];
  const float* Wk = (const float*)d_in[2];
  const float* Wv = (const float*)d_in[3];
  const float* Wo = (const float*)d_in[4];

  char* ws = (char*)d_ws;
  ushort* xb  = (ushort*)(ws + 0);           // 32 MiB  [Mtot, En]
  ushort* wqb = (ushort*)(ws + 33554432);    // 8 MiB
  ushort* wkb = (ushort*)(ws + 41943040);
  ushort* wvb = (ushort*)(ws + 50331648);
  ushort* wob = (ushort*)(ws + 58720256);
  ushort* Qb  = (ushort*)(ws + 67108864);    // 32 MiB
  ushort* Kb  = (ushort*)(ws + 100663296);   // 32 MiB
  ushort* Vt  = (ushort*)(ws + 134217728);   // 32 MiB  [B*En, Sn]
  ushort* Ab  = xb;                           // alias: xb dead after V GEMM

  cvt_kernel<<<dim3(Mtot * En / 1024), 256, 0, stream>>>(x, xb);
  cvt_kernel<<<dim3(En * En / 1024), 256, 0, stream>>>(Wq, wqb);
  cvt_kernel<<<dim3(En * En / 1024), 256, 0, stream>>>(Wk, wkb);
  cvt_kernel<<<dim3(En * En / 1024), 256, 0, stream>>>(Wv, wvb);
  cvt_kernel<<<dim3(En * En / 1024), 256, 0, stream>>>(Wo, wob);

  dim3 ggrid(En / 128, Mtot / 128);
  gemm_bt<0><<<ggrid, 256, 0, stream>>>(xb, wqb, (void*)Qb);
  gemm_bt<0><<<ggrid, 256, 0, stream>>>(xb, wkb, (void*)Kb);
  gemm_bt<1><<<ggrid, 256, 0, stream>>>(xb, wvb, (void*)Vt);

  // scale folded into Q: 1/sqrt(128) * log2(e)
  rope_kernel<<<dim3(Mtot), 256, 0, stream>>>(Qb, 0.08838834764831845f * 1.4426950408889634f);
  rope_kernel<<<dim3(Mtot), 256, 0, stream>>>(Kb, 1.0f);

  flash_kernel<<<dim3(Sn / 128, Bn * Hn), 256, 0, stream>>>(Qb, Kb, Vt, Ab);

  gemm_bt<2><<<ggrid, 256, 0, stream>>>(Ab, wob, d_out);
}

// Round 4
// 1166.318 us; speedup vs baseline: 1.5815x; 1.0268x over previous
//
#include <hip/hip_runtime.h>

typedef float f32x4 __attribute__((ext_vector_type(4)));
typedef short bf16x8 __attribute__((ext_vector_type(8)));

#define DEVI __device__ __forceinline__

// ---------- constants (problem shape is fixed) ----------
constexpr int Bn = 2;          // batch
constexpr int Sn = 4096;       // seq
constexpr int Hn = 16;         // heads
constexpr int Dn = 128;        // head dim
constexpr int En = 2048;       // d_model = Hn*Dn
constexpr int Mtot = Bn * Sn;  // 8192 token rows

DEVI unsigned short f2bf(float f) {
  unsigned u = __float_as_uint(f);
  u += 0x7fffu + ((u >> 16) & 1u);
  return (unsigned short)(u >> 16);
}
DEVI float bf2f(unsigned short h) {
  return __uint_as_float(((unsigned)h) << 16);
}

DEVI void async16(const void* g, void* l) {
  __builtin_amdgcn_global_load_lds(
      (const __attribute__((address_space(1))) void*)g,
      (__attribute__((address_space(3))) void*)l, 16, 0, 0);
}

// ---------- fp32 -> bf16 convert ----------
__global__ void cvt_kernel(const float* __restrict__ in, ushort* __restrict__ out) {
  size_t i = ((size_t)blockIdx.x * 256 + threadIdx.x) * 4;
  float4 v = *(const float4*)&in[i];
  ushort4 o;
  o.x = f2bf(v.x); o.y = f2bf(v.y); o.z = f2bf(v.z); o.w = f2bf(v.w);
  *(ushort4*)&out[i] = o;
}

// ---------- RoPE in place on [Mtot, En] bf16, interleaved pairs ----------
__global__ void rope_kernel(ushort* __restrict__ Q, float scale) {
  int row = blockIdx.x;           // 0..Mtot-1
  int s = row & (Sn - 1);
  int t = threadIdx.x;
  size_t base = (size_t)row * En;
#pragma unroll
  for (int rep = 0; rep < 4; ++rep) {
    int p = rep * 256 + t;        // pair index 0..1023
    int e = p * 2;
    int pp = (e & (Dn - 1)) >> 1; // pair index within head, 0..63
    float inv = exp2f(-(float)pp * (13.287712379549449f / 64.0f));
    float ang = (float)s * inv;
    float c = cosf(ang), sn = sinf(ang);
    unsigned v = *(unsigned*)&Q[base + e];
    float q0 = bf2f((unsigned short)(v & 0xffffu));
    float q1 = bf2f((unsigned short)(v >> 16));
    float n0 = (q0 * c - q1 * sn) * scale;
    float n1 = (q1 * c + q0 * sn) * scale;
    unsigned outv = (unsigned)f2bf(n0) | ((unsigned)f2bf(n1) << 16);
    *(unsigned*)&Q[base + e] = outv;
  }
}

// ---------- GEMM: C[M,N] = A[M,K] * B[N,K]^T, bf16 in, fp32 acc ----------
template <int EPI>
__global__ __launch_bounds__(256) void gemm_bt(const ushort* __restrict__ A,
                                               const ushort* __restrict__ Bm,
                                               void* __restrict__ Cv) {
  __shared__ ushort As[128 * 64];
  __shared__ ushort Bs[128 * 64];
  const int t = threadIdx.x;
  const int lane = t & 63, w = t >> 6;
  const int ln = lane & 15, gq = lane >> 4;
  const int m0 = blockIdx.y * 128, n0 = blockIdx.x * 128;
  const int rm = (w >> 1) * 64, rn = (w & 1) * 64;
  f32x4 acc[4][4] = {};

  for (int k0 = 0; k0 < En; k0 += 64) {
#pragma unroll
    for (int rep = 0; rep < 4; ++rep) {
      int c = rep * 256 + t;       // chunk 0..1023 (16B each)
      int row = c >> 3, c8 = c & 7;
      async16(&A[(size_t)(m0 + row) * En + k0 + c8 * 8],
              (char*)As + (rep * 256 + w * 64) * 16);
      async16(&Bm[(size_t)(n0 + row) * En + k0 + c8 * 8],
              (char*)Bs + (rep * 256 + w * 64) * 16);
    }
    __syncthreads();
#pragma unroll
    for (int kk = 0; kk < 64; kk += 32) {
      bf16x8 af[4], bf[4];
#pragma unroll
      for (int i = 0; i < 4; ++i)
        af[i] = *(const bf16x8*)&As[(rm + i * 16 + ln) * 64 + kk + gq * 8];
#pragma unroll
      for (int j = 0; j < 4; ++j)
        bf[j] = *(const bf16x8*)&Bs[(rn + j * 16 + ln) * 64 + kk + gq * 8];
#pragma unroll
      for (int i = 0; i < 4; ++i)
#pragma unroll
        for (int j = 0; j < 4; ++j)
          acc[i][j] = __builtin_amdgcn_mfma_f32_16x16x32_bf16(af[i], bf[j], acc[i][j], 0, 0, 0);
    }
    __syncthreads();
  }

  if constexpr (EPI == 0) {
    ushort* C = (ushort*)Cv;
#pragma unroll
    for (int i = 0; i < 4; ++i) {
      int row0 = m0 + rm + i * 16 + gq * 4;
#pragma unroll
      for (int j = 0; j < 4; ++j) {
        int col = n0 + rn + j * 16 + ln;
#pragma unroll
        for (int r = 0; r < 4; ++r)
          C[(size_t)(row0 + r) * En + col] = f2bf(acc[i][j][r]);
      }
    }
  } else if constexpr (EPI == 1) {
    ushort* Vt = (ushort*)Cv;
#pragma unroll
    for (int i = 0; i < 4; ++i) {
      int mrow = m0 + rm + i * 16 + gq * 4;   // token row (4 consecutive)
      int bb = mrow >> 12;                     // /Sn
      int ss = mrow & (Sn - 1);
#pragma unroll
      for (int j = 0; j < 4; ++j) {
        int col = n0 + rn + j * 16 + ln;       // e = h*128+d
        ushort4 pk;
        pk.x = f2bf(acc[i][j][0]); pk.y = f2bf(acc[i][j][1]);
        pk.z = f2bf(acc[i][j][2]); pk.w = f2bf(acc[i][j][3]);
        *(ushort4*)&Vt[((size_t)(bb * En + col)) * Sn + ss] = pk;
      }
    }
  } else {
    float* C = (float*)Cv;
#pragma unroll
    for (int i = 0; i < 4; ++i) {
      int row0 = m0 + rm + i * 16 + gq * 4;
#pragma unroll
      for (int j = 0; j < 4; ++j) {
        int col = n0 + rn + j * 16 + ln;
#pragma unroll
        for (int r = 0; r < 4; ++r)
          C[(size_t)(row0 + r) * En + col] = acc[i][j][r];
      }
    }
  }
}

// ---------- flash attention (causal), S^T formulation, R4 ----------
// global_load_lds staging (zero reg pressure, DMA LDS writes = no staging
// conflicts) with XOR-swizzled K/V layout (conflict-free fragment reads,
// no padding needed despite wave-linear DMA constraint).
//   Ks: [kv j 0..63][d chunk sc 0..15], chunk c stored at sc=(c&8)|((c^j)&7)
//   Vs: [d 0..127][kv chunk sc 0..7],   chunk c stored at sc=(c^d)&7
//   Ps: per-wave P [q i][kv j], padded stride 72 (VALU writes, uniform banks)
__global__ __launch_bounds__(256) void flash_kernel(const ushort* __restrict__ Qb,
                                                    const ushort* __restrict__ Kb,
                                                    const ushort* __restrict__ Vt,
                                                    ushort* __restrict__ Ab) {
  __shared__ ushort Ks[64 * 128];
  __shared__ ushort Vs[128 * 64];
  __shared__ ushort Ps[4][32 * 72];
  const int t = threadIdx.x;
  const int lane = t & 63, w = t >> 6;
  const int ln = lane & 15, gq = lane >> 4;
  const int qt = gridDim.x - 1 - blockIdx.x;   // heavy tiles dispatch first
  const int q0 = qt * 128;
  const int bh = blockIdx.y;
  const int b = bh >> 4, h = bh & 15;

  // Q fragments (B-operand), already scaled by 1/sqrt(D)*log2(e) in RoPE.
  bf16x8 qf[2][4];
#pragma unroll
  for (int it = 0; it < 2; ++it) {
    int qrow = q0 + w * 32 + it * 16 + ln;
    size_t base = ((size_t)(b * Sn + qrow)) * En + h * Dn;
#pragma unroll
    for (int ks = 0; ks < 4; ++ks)
      qf[it][ks] = *(const bf16x8*)&Qb[base + ks * 32 + gq * 8];
  }

  f32x4 o[8][2] = {};                 // O^T acc: [dt][it]
  float m_prev[2] = {-1e30f, -1e30f};
  float l_prev[2] = {0.f, 0.f};
  const int jmax = q0 + 64;

  for (int j0 = 0; j0 <= jmax; j0 += 64) {
    __syncthreads();   // all waves done reading previous tile
    // DMA-stage K and V tiles with inverse-swizzled global addressing.
#pragma unroll
    for (int rep = 0; rep < 4; ++rep) {
      int cl = rep * 256 + t;
      {  // Ks chunk cl: row r = cl>>4, stored col sc = cl&15 -> logical c
        int r = cl >> 4, sc = cl & 15;
        int c = (sc & 8) | ((sc ^ r) & 7);
        async16(&Kb[((size_t)(b * Sn + j0 + r)) * En + h * Dn + c * 8],
                (char*)Ks + (rep * 256 + w * 64) * 16);
      }
      {  // Vs chunk cl: row r = cl>>3, stored col sc = cl&7 -> logical c
        int r = cl >> 3, sc = cl & 7;
        int c = (sc ^ r) & 7;
        async16(&Vt[((size_t)(b * En + h * Dn + r)) * Sn + j0 + c * 8],
                (char*)Vs + (rep * 256 + w * 64) * 16);
      }
    }
    __syncthreads();   // staged tiles visible

    const bool active = (j0 <= q0 + w * 32 + 31);   // wave-uniform
    if (active) {
      // S^T tiles: C[m=j][n=i]
      f32x4 s[2][4] = {};
#pragma unroll
      for (int jt = 0; jt < 4; ++jt) {
        int row = jt * 16 + ln;
#pragma unroll
        for (int ks = 0; ks < 4; ++ks) {
          int c = ks * 4 + gq;
          int sc = (c & 8) | ((c ^ ln) & 7);
          bf16x8 kf = *(const bf16x8*)&Ks[row * 128 + sc * 8];
          s[0][jt] = __builtin_amdgcn_mfma_f32_16x16x32_bf16(kf, qf[0][ks], s[0][jt], 0, 0, 0);
          s[1][jt] = __builtin_amdgcn_mfma_f32_16x16x32_bf16(kf, qf[1][ks], s[1][jt], 0, 0, 0);
        }
      }

      // online softmax per q column (lane owns column i = ln)
#pragma unroll
      for (int it = 0; it < 2; ++it) {
        int qrow = q0 + w * 32 + it * 16 + ln;
        bool needmask = (j0 + 63 > q0 + w * 32 + it * 16);  // wave-uniform
        float mx = -1e30f;
        if (needmask) {
#pragma unroll
          for (int jt = 0; jt < 4; ++jt)
#pragma unroll
            for (int r = 0; r < 4; ++r) {
              int j = j0 + jt * 16 + gq * 4 + r;
              float v = s[it][jt][r];
              v = (j > qrow) ? -1e30f : v;
              s[it][jt][r] = v;
              mx = fmaxf(mx, v);
            }
        } else {
#pragma unroll
          for (int jt = 0; jt < 4; ++jt)
#pragma unroll
            for (int r = 0; r < 4; ++r) mx = fmaxf(mx, s[it][jt][r]);
        }
        mx = fmaxf(mx, __shfl_xor(mx, 16));
        mx = fmaxf(mx, __shfl_xor(mx, 32));
        float mn = fmaxf(m_prev[it], mx);
        float alpha = __builtin_amdgcn_exp2f(m_prev[it] - mn);
        float sum = 0.f;
#pragma unroll
        for (int jt = 0; jt < 4; ++jt) {
#pragma unroll
          for (int r = 0; r < 4; ++r) {
            float p = __builtin_amdgcn_exp2f(s[it][jt][r] - mn);
            s[it][jt][r] = p;
            sum += p;
          }
        }
        sum += __shfl_xor(sum, 16);
        sum += __shfl_xor(sum, 32);
        l_prev[it] = l_prev[it] * alpha + sum;
        m_prev[it] = mn;
#pragma unroll
        for (int dt = 0; dt < 8; ++dt) o[dt][it] *= alpha;
#pragma unroll
        for (int jt = 0; jt < 4; ++jt) {
          ushort4 pk;
          pk.x = f2bf(s[it][jt][0]); pk.y = f2bf(s[it][jt][1]);
          pk.z = f2bf(s[it][jt][2]); pk.w = f2bf(s[it][jt][3]);
          *(ushort4*)&Ps[w][(it * 16 + ln) * 72 + jt * 16 + gq * 4] = pk;
        }
      }

      // PV: O^T[d][i] += sum_j Vs[d][j] * P[i][j]
#pragma unroll
      for (int ksj = 0; ksj < 2; ++ksj) {
        bf16x8 pf[2];
#pragma unroll
        for (int it = 0; it < 2; ++it)
          pf[it] = *(const bf16x8*)&Ps[w][(it * 16 + ln) * 72 + ksj * 32 + gq * 8];
#pragma unroll
        for (int dt = 0; dt < 8; ++dt) {
          int row = dt * 16 + ln;
          int c = ksj * 4 + gq;
          int sc = (c ^ ln) & 7;
          bf16x8 vf = *(const bf16x8*)&Vs[row * 64 + sc * 8];
          o[dt][0] = __builtin_amdgcn_mfma_f32_16x16x32_bf16(vf, pf[0], o[dt][0], 0, 0, 0);
          o[dt][1] = __builtin_amdgcn_mfma_f32_16x16x32_bf16(vf, pf[1], o[dt][1], 0, 0, 0);
        }
      }
    }
  }

  // epilogue: normalize by 1/l, write Ab[b, qrow, h*128 + d]
#pragma unroll
  for (int it = 0; it < 2; ++it) {
    float inv = 1.f / l_prev[it];
    int qrow = q0 + w * 32 + it * 16 + ln;
    size_t base = ((size_t)(b * Sn + qrow)) * En + h * Dn;
#pragma unroll
    for (int dt = 0; dt < 8; ++dt) {
      ushort4 pk;
      pk.x = f2bf(o[dt][it][0] * inv);
      pk.y = f2bf(o[dt][it][1] * inv);
      pk.z = f2bf(o[dt][it][2] * inv);
      pk.w = f2bf(o[dt][it][3] * inv);
      *(ushort4*)&Ab[base + dt * 16 + gq * 4] = pk;
    }
  }
}

extern "C" void kernel_launch(void* const* d_in, const int* in_sizes, int n_in,
                              void* d_out, int out_size, void* d_ws, size_t ws_size,
                              hipStream_t stream) {
  const float* x  = (const float*)d_in[0];
  const float* Wq = (const float*)d_in[1];
  const float* Wk = (const float*)d_in[2];
  const float* Wv = (const float*)d_in[3];
  const float* Wo = (const float*)d_in[4];

  char* ws = (char*)d_ws;
  ushort* xb  = (ushort*)(ws + 0);           // 32 MiB  [Mtot, En]
  ushort* wqb = (ushort*)(ws + 33554432);    // 8 MiB
  ushort* wkb = (ushort*)(ws + 41943040);
  ushort* wvb = (ushort*)(ws + 50331648);
  ushort* wob = (ushort*)(ws + 58720256);
  ushort* Qb  = (ushort*)(ws + 67108864);    // 32 MiB
  ushort* Kb  = (ushort*)(ws + 100663296);   // 32 MiB
  ushort* Vt  = (ushort*)(ws + 134217728);   // 32 MiB  [B*En, Sn]
  ushort* Ab  = xb;                           // alias: xb dead after V GEMM

  cvt_kernel<<<dim3(Mtot * En / 1024), 256, 0, stream>>>(x, xb);
  cvt_kernel<<<dim3(En * En / 1024), 256, 0, stream>>>(Wq, wqb);
  cvt_kernel<<<dim3(En * En / 1024), 256, 0, stream>>>(Wk, wkb);
  cvt_kernel<<<dim3(En * En / 1024), 256, 0, stream>>>(Wv, wvb);
  cvt_kernel<<<dim3(En * En / 1024), 256, 0, stream>>>(Wo, wob);

  dim3 ggrid(En / 128, Mtot / 128);
  gemm_bt<0><<<ggrid, 256, 0, stream>>>(xb, wqb, (void*)Qb);
  gemm_bt<0><<<ggrid, 256, 0, stream>>>(xb, wkb, (void*)Kb);
  gemm_bt<1><<<ggrid, 256, 0, stream>>>(xb, wvb, (void*)Vt);

  // scale folded into Q: 1/sqrt(128) * log2(e)
  rope_kernel<<<dim3(Mtot), 256, 0, stream>>>(Qb, 0.08838834764831845f * 1.4426950408889634f);
  rope_kernel<<<dim3(Mtot), 256, 0, stream>>>(Kb, 1.0f);

  flash_kernel<<<dim3(Sn / 128, Bn * Hn), 256, 0, stream>>>(Qb, Kb, Vt, Ab);

  gemm_bt<2><<<ggrid, 256, 0, stream>>>(Ab, wob, d_out);
}